// Round 5
// baseline (934.695 us; speedup 1.0000x reference)
//
#include <hip/hip_runtime.h>

// ---------------- problem constants ----------------
#define T_SEQ 4096
#define BATCH 4
#define NH 16
#define M_ROWS 16384

typedef __attribute__((ext_vector_type(8))) short short8;
typedef __attribute__((ext_vector_type(4))) float floatx4;

__device__ __forceinline__ float b2f(unsigned short u) {
    union { unsigned int i; float f; } x; x.i = ((unsigned int)u) << 16; return x.f;
}
__device__ __forceinline__ unsigned short f2b(float f) {
    union { float f; unsigned int i; } x; x.f = f;
    unsigned int u = x.i;
    u += 0x7fffu + ((u >> 16) & 1u);   // RNE
    return (unsigned short)(u >> 16);
}

__device__ __forceinline__ void store_out(float* p, float v) { *p = v; }
__device__ __forceinline__ void store_out(unsigned short* p, float v) { *p = f2b(v); }

// load 16 contiguous elements as bf16 (convert when source is f32)
__device__ __forceinline__ void ldconv16(const float* p, uint4& lo, uint4& hi) {
    float4 f0 = *(const float4*)(p);
    float4 f1 = *(const float4*)(p + 4);
    float4 f2 = *(const float4*)(p + 8);
    float4 f3 = *(const float4*)(p + 12);
    unsigned short u[16];
    u[0] = f2b(f0.x); u[1] = f2b(f0.y); u[2]  = f2b(f0.z); u[3]  = f2b(f0.w);
    u[4] = f2b(f1.x); u[5] = f2b(f1.y); u[6]  = f2b(f1.z); u[7]  = f2b(f1.w);
    u[8] = f2b(f2.x); u[9] = f2b(f2.y); u[10] = f2b(f2.z); u[11] = f2b(f2.w);
    u[12] = f2b(f3.x); u[13] = f2b(f3.y); u[14] = f2b(f3.z); u[15] = f2b(f3.w);
    lo = *(uint4*)u; hi = *(uint4*)(u + 8);
}
__device__ __forceinline__ void ldconv16(const unsigned short* p, uint4& lo, uint4& hi) {
    lo = *(const uint4*)p; hi = *(const uint4*)(p + 8);
}

// ---------------- weight transpose+convert: W[K][N] f32 -> Wt[N][K] bf16 ----------------
__global__ __launch_bounds__(256) void transpose_w(
    const float* __restrict__ wq,
    const float* __restrict__ wkv,
    const float* __restrict__ wout,
    unsigned short* __restrict__ wqT,
    unsigned short* __restrict__ wkvT,
    unsigned short* __restrict__ woutT)
{
    int bid = blockIdx.x;
    const float* src; unsigned short* dst; int Nd; int local;
    if (bid < 1024)      { src = wq;   dst = wqT;   Nd = 1024; local = bid; }
    else if (bid < 3072) { src = wkv;  dst = wkvT;  Nd = 2048; local = bid - 1024; }
    else                 { src = wout; dst = woutT; Nd = 1024; local = bid - 3072; }
    int tilesN = Nd >> 5;
    int tk = local / tilesN, tn = local % tilesN;
    __shared__ __align__(16) unsigned short tile[32][36];
    int tid = threadIdx.x;
    int r = tid >> 3, c = (tid & 7) * 4;
    float4 in = *(const float4*)(src + (long)(tk * 32 + r) * Nd + tn * 32 + c);
    tile[r][c] = f2b(in.x); tile[r][c + 1] = f2b(in.y);
    tile[r][c + 2] = f2b(in.z); tile[r][c + 3] = f2b(in.w);
    __syncthreads();
    ushort4 o;
    o.x = tile[c][r]; o.y = tile[c + 1][r]; o.z = tile[c + 2][r]; o.w = tile[c + 3][r];
    *(ushort4*)(dst + (long)(tn * 32 + r) * 1024 + tk * 32 + c) = o;
}

// ---------------- bf16 MFMA GEMM: C[M,N] = A[M,K] * Bt[N,K]^T + bias ----------------
// A f32 or bf16 (converted to bf16 during LDS staging). Bt bf16. bias f32. C f32 or bf16.
#define BM 128
#define BN 128
#define BKK 32
#define LDST 40   // LDS row stride (bf16 elems)

template <typename AT, typename OT>
__global__ __launch_bounds__(256) void gemm_bt(
    const AT* __restrict__ A,                // [M,K] row-major
    const unsigned short* __restrict__ Bt,   // [N,K] bf16 row-major (B transposed)
    const float* __restrict__ bias,          // [N] f32
    OT* __restrict__ C,                      // [M,N]
    int N, int K)
{
    __shared__ __align__(16) unsigned short As[BM * LDST];
    __shared__ __align__(16) unsigned short Bs[BN * LDST];
    const int tid  = threadIdx.x;
    const int bm   = blockIdx.y, bn = blockIdx.x;
    const int w    = tid >> 6, lane = tid & 63;
    const int wm   = (w >> 1) * 64, wn = (w & 1) * 64;
    const int l16  = lane & 15, quad = lane >> 4;
    const int srow = tid >> 1, soff = (tid & 1) * 16;

    const AT* pa             = A  + (long)(bm * BM + srow) * K + soff;
    const unsigned short* pb = Bt + (long)(bn * BN + srow) * K + soff;
    unsigned short* wa = &As[srow * LDST + soff];
    unsigned short* wb = &Bs[srow * LDST + soff];

    floatx4 acc[4][4] = {};

    for (int k0 = 0; k0 < K; k0 += BKK) {
        uint4 alo, ahi, blo, bhi;
        ldconv16(pa, alo, ahi);
        ldconv16(pb, blo, bhi);
        pa += BKK; pb += BKK;
        __syncthreads();                 // prior iter's LDS reads done
        *(uint4*)(wa)     = alo; *(uint4*)(wa + 8) = ahi;
        *(uint4*)(wb)     = blo; *(uint4*)(wb + 8) = bhi;
        __syncthreads();
        short8 af[4], bf[4];
#pragma unroll
        for (int i = 0; i < 4; i++) {
            af[i] = *(const short8*)&As[(wm + i * 16 + l16) * LDST + quad * 8];
            bf[i] = *(const short8*)&Bs[(wn + i * 16 + l16) * LDST + quad * 8];
        }
#pragma unroll
        for (int i = 0; i < 4; i++)
#pragma unroll
            for (int j = 0; j < 4; j++)
                acc[i][j] = __builtin_amdgcn_mfma_f32_16x16x32_bf16(af[i], bf[j], acc[i][j], 0, 0, 0);
    }

#pragma unroll
    for (int i = 0; i < 4; i++) {
        int m0 = bm * BM + wm + i * 16 + quad * 4;
#pragma unroll
        for (int j = 0; j < 4; j++) {
            int n = bn * BN + wn + j * 16 + l16;
            float bv = bias[n];
            long base = (long)m0 * N + n;
#pragma unroll
            for (int r = 0; r < 4; r++)
                store_out(C + base + (long)r * N, acc[i][j][r] + bv);
        }
    }
}

// ---------------- softmax stats over time axis: per (b, d) column of k ----------------
__global__ __launch_bounds__(256) void softmax_stats(
    const unsigned short* __restrict__ kvb,  // [M,2048] bf16; k = cols 0..1023
    float* __restrict__ mout, float* __restrict__ isout)
{
    int b = blockIdx.y;
    int d = blockIdx.x * 64 + (threadIdx.x & 63);
    int tl = threadIdx.x >> 6;
    const unsigned short* p = kvb + (long)b * T_SEQ * 2048 + d;
    float m = -1e30f, s = 0.0f;
    for (int t = tl; t < T_SEQ; t += 4) {
        float v = b2f(p[(long)t * 2048]);
        if (v > m) { s = s * __expf(m - v) + 1.0f; m = v; }
        else       { s += __expf(v - m); }
    }
    __shared__ float sm[256], ss[256];
    sm[threadIdx.x] = m; ss[threadIdx.x] = s;
    __syncthreads();
    if (tl == 0) {
        int c = threadIdx.x;
        float M = sm[c], S = ss[c];
#pragma unroll
        for (int q = 1; q < 4; q++) {
            float m2 = sm[q * 64 + c], s2 = ss[q * 64 + c];
            float nm = fmaxf(M, m2);
            S = S * __expf(M - nm) + s2 * __expf(m2 - nm);
            M = nm;
        }
        mout[b * 1024 + d]  = M;
        isout[b * 1024 + d] = 1.0f / S;
    }
}

// ---------------- context[b,h,d,e] = sum_t softmax_k[t,d] * v[t,e] ----------------
__global__ __launch_bounds__(256) void context_kernel(
    const unsigned short* __restrict__ kvb,
    const float* __restrict__ mbuf, const float* __restrict__ isbuf,
    float* __restrict__ ctx)   // [B,H,64,64] f32, pre-zeroed
{
    int chunk = blockIdx.x;        // 0..7, each covers 512 t
    int h = blockIdx.y, b = blockIdx.z;
    __shared__ float Ks[16][64];
    __shared__ float Vs[16][64];
    __shared__ float msh[64], ish[64];
    int tid = threadIdx.x;
    if (tid < 64) {
        msh[tid] = mbuf[b * 1024 + h * 64 + tid];
        ish[tid] = isbuf[b * 1024 + h * 64 + tid];
    }
    __syncthreads();
    int srow = tid >> 4;
    int scol = (tid & 15) * 8;
    int td = tid & 15, te = tid >> 4;
    long colbase = (scol < 64) ? (long)(h * 64 + scol) : (long)(1024 + h * 64 + scol - 64);
    float acc[4][4] = {};

    for (int t0 = chunk * 512; t0 < (chunk + 1) * 512; t0 += 16) {
        uint4 raw = *(const uint4*)(kvb + (long)(b * T_SEQ + t0 + srow) * 2048 + colbase);
        unsigned short u[8];
        *(uint4*)u = raw;
        if (scol < 64) {
#pragma unroll
            for (int j = 0; j < 8; j++)
                Ks[srow][scol + j] = __expf(b2f(u[j]) - msh[scol + j]) * ish[scol + j];
        } else {
#pragma unroll
            for (int j = 0; j < 8; j++)
                Vs[srow][scol - 64 + j] = b2f(u[j]);
        }
        __syncthreads();
#pragma unroll
        for (int t = 0; t < 16; t++) {
            float k4[4], v4[4];
#pragma unroll
            for (int i = 0; i < 4; i++) k4[i] = Ks[t][td * 4 + i];
#pragma unroll
            for (int j = 0; j < 4; j++) v4[j] = Vs[t][te * 4 + j];
#pragma unroll
            for (int i = 0; i < 4; i++)
#pragma unroll
                for (int j = 0; j < 4; j++) acc[i][j] = fmaf(k4[i], v4[j], acc[i][j]);
        }
        __syncthreads();
    }
    float* cb = ctx + (long)(b * NH + h) * 4096;
#pragma unroll
    for (int i = 0; i < 4; i++)
#pragma unroll
        for (int j = 0; j < 4; j++)
            atomicAdd(&cb[(td * 4 + i) * 64 + te * 4 + j], acc[i][j]);
}

// ---------------- attn: q[t,h,:] @ context[h] -> overwrite q buffer in place ----------------
__global__ __launch_bounds__(256) void attn_apply(
    unsigned short* __restrict__ qb,        // [M,1024] bf16, overwritten with result
    const float* __restrict__ ctx)
{
    int tc = blockIdx.x, h = blockIdx.y, b = blockIdx.z;
    __shared__ __align__(16) float Cs[64][64];   // [d][e]
    __shared__ __align__(16) float Qs[64][64];   // [t][d]
    int tid = threadIdx.x;
    const float* cb = ctx + (long)(b * NH + h) * 4096;
#pragma unroll
    for (int i = 0; i < 4; i++) {
        int idx = i * 256 + tid;
        ((float4*)Cs)[idx] = ((const float4*)cb)[idx];
    }
    int srow = tid >> 2, scol = (tid & 3) * 16;
    const unsigned short* qp = qb + (long)(b * T_SEQ + tc * 64 + srow) * 1024 + h * 64 + scol;
    uint4 r0 = *(const uint4*)qp;
    uint4 r1 = *(const uint4*)(qp + 8);
    unsigned short u[16];
    *(uint4*)u = r0; *(uint4*)(u + 8) = r1;
#pragma unroll
    for (int j = 0; j < 16; j++) Qs[srow][scol + j] = b2f(u[j]);
    __syncthreads();                 // all global reads staged before in-place writes
    int e = tid & 63, tq = tid >> 6;
#pragma unroll 4
    for (int ti = 0; ti < 16; ti++) {
        int t = tq * 16 + ti;
        float acc = 0.f;
#pragma unroll
        for (int dd = 0; dd < 64; dd++) acc = fmaf(Qs[t][dd], Cs[dd][e], acc);
        qb[(long)(b * T_SEQ + tc * 64 + t) * 1024 + h * 64 + e] = f2b(acc);
    }
}

// ---------------- launch ----------------
extern "C" void kernel_launch(void* const* d_in, const int* in_sizes, int n_in,
                              void* d_out, int out_size, void* d_ws, size_t ws_size,
                              hipStream_t stream) {
    const float* x     = (const float*)d_in[0];
    const float* z     = (const float*)d_in[1];
    const float* w_q   = (const float*)d_in[2];
    const float* b_q   = (const float*)d_in[3];
    const float* w_kv  = (const float*)d_in[4];
    const float* b_kv  = (const float*)d_in[5];
    const float* w_out = (const float*)d_in[6];
    const float* b_out = (const float*)d_in[7];
    float* out = (float*)d_out;            // reference output dtype is float32

    char* ws = (char*)d_ws;
    unsigned short* kvb   = (unsigned short*)(ws);                  // [16384,2048] bf16 = 64 MB
    unsigned short* qb    = (unsigned short*)(ws + 67108864);       // [16384,1024] bf16 = 32 MB
    unsigned short* wqT   = (unsigned short*)(ws + 100663296);      // 2 MB
    unsigned short* wkvT  = (unsigned short*)(ws + 102760448);      // 4 MB
    unsigned short* woutT = (unsigned short*)(ws + 106954752);      // 2 MB
    float* mbuf  = (float*)(ws + 109051904);                        // 16 KB
    float* isbuf = (float*)(ws + 109068288);                        // 16 KB
    float* ctx   = (float*)(ws + 109084672);                        // 256 KB
    // peak ~104.3 MiB (same layout class as round 2/4, which ran without fault)

    hipMemsetAsync(ctx, 0, (size_t)BATCH * NH * 64 * 64 * 4, stream);
    transpose_w<<<4096, 256, 0, stream>>>(w_q, w_kv, w_out, wqT, wkvT, woutT);
    // q = x @ w_q + b_q   [16384,1024] bf16
    gemm_bt<float, unsigned short><<<dim3(8, 128), 256, 0, stream>>>(x, wqT, b_q, qb, 1024, 1024);
    // kv = z @ w_kv + b_kv   [16384,2048] bf16
    gemm_bt<float, unsigned short><<<dim3(16, 128), 256, 0, stream>>>(z, wkvT, b_kv, kvb, 2048, 1024);
    softmax_stats<<<dim3(16, BATCH), 256, 0, stream>>>(kvb, mbuf, isbuf);
    context_kernel<<<dim3(8, NH, BATCH), 256, 0, stream>>>(kvb, mbuf, isbuf, ctx);
    attn_apply<<<dim3(T_SEQ / 64, NH, BATCH), 256, 0, stream>>>(qb, ctx);
    // out = attn @ w_out + b_out   [16384,1024] f32 -> d_out
    gemm_bt<unsigned short, float><<<dim3(8, 128), 256, 0, stream>>>(qb, woutT, b_out, out, 1024, 1024);
}